// Round 10
// baseline (1093.057 us; speedup 1.0000x reference)
//
#include <hip/hip_runtime.h>
#include <hip/hip_bf16.h>
#include <stdint.h>

#define BB 64
#define SS 2048
#define TT 128
#define GRP 3              // em prefetch group depth (3-6 steps of latency cover)

typedef int    i32x8 __attribute__((ext_vector_type(8)));
typedef float  f32x4 __attribute__((ext_vector_type(4)));

// Raw workgroup barrier that does NOT drain vmcnt (LDS ordering only).
__device__ __forceinline__ void wg_barrier_lds() {
    asm volatile("" ::: "memory");
    __builtin_amdgcn_s_waitcnt(0xc07f);   // lgkmcnt(0), vmcnt/expcnt no-wait
    __builtin_amdgcn_s_barrier();
    asm volatile("" ::: "memory");
}

// ---- bool-layout detection: mask[0,0] is always true (len >= 1024) ----
__device__ __forceinline__ int detect_mode(const void* maskp) {
    uint32_t w0 = ((const uint32_t*)maskp)[0];
    if (w0 == 1u) return 0;
    if (w0 == 0x3F800000u) return 2;
    if (w0 == 0x3F803F80u) return 3;
    return 1;
}
__device__ __forceinline__ int mask_at(const void* maskp, int mode, size_t idx) {
    if (mode == 0) return ((const int*)maskp)[idx] != 0;
    if (mode == 1) return ((const unsigned char*)maskp)[idx] != 0;
    if (mode == 2) return ((const float*)maskp)[idx] != 0.f;
    return ((const unsigned short*)maskp)[idx] != 0;
}

// ---- MX-fp8 K=128 scan, ONE barrier/step, EXACT per-wave pow2 renorm ----
// Wave w renorms its 32-row block by its own exact max (no cross-wave wait);
// the cross-wave scale mismatch 2^(R_q - R_w) is repaid inside the MFMA via
// the per-lane E8M0 block-scale operand (lane quad q <-> k-block q).
__global__ __launch_bounds__(256, 1) void fwd_kernel(
    const float* __restrict__ em, const void* __restrict__ maskp,
    const int* __restrict__ tags, const void* __restrict__ forb,
    const float* __restrict__ trans,
    const float* __restrict__ startt, const float* __restrict__ endt,
    double* __restrict__ zout, double* __restrict__ postout)
{
    const int t = threadIdx.x;
    const int w = t >> 6;          // wave 0..3 (owns u rows 32w..32w+31)
    const int lane = t & 63;
    const int q = lane >> 4;       // quad 0..3 (k-block / D row group)
    const int c = lane & 15;       // MFMA m/n column (n replicated)
    const int b = blockIdx.x;      // the batch

    __shared__ __align__(16) int u8i[2][32];   // double-buffered u, fp8 (128 B each)
    __shared__ __align__(16) int rS[2][4];     // double-buffered per-wave scale deltas
    __shared__ int    redi[4];
    __shared__ double redd[4];
    __shared__ int    redc[4];

    const int mode = detect_mode(maskp);

    // ---- length of this batch (contiguous mask prefix) ----
    {
        int cnt = 0;
        for (int s = t; s < SS; s += 256) cnt += mask_at(maskp, mode, (size_t)b * SS + s);
        #pragma unroll
        for (int off = 32; off >= 1; off >>= 1) cnt += __shfl_xor(cnt, off);
        if (lane == 0) redi[w] = cnt;
    }
    __syncthreads();
    const int len = redi[0] + redi[1] + redi[2] + redi[3];

    // ---- E^T A-fragments in fp8 (register-resident) ----
    // A[m=c][k=32q+4d+jj] of tile (2w+ml): E[32q+4d+jj][32w+16ml+c]
    i32x8 afrag[2];
    #pragma unroll
    for (int ml = 0; ml < 2; ++ml) {
        int col = 32 * w + 16 * ml + c;
        #pragma unroll
        for (int d = 0; d < 8; ++d) {
            float x[4];
            #pragma unroll
            for (int jj = 0; jj < 4; ++jj) {
                size_t idx = (size_t)(32 * q + 4 * d + jj) * TT + col;
                x[jj] = mask_at(forb, mode, idx) ? 0.f : __expf(trans[idx]);
            }
            int dw = __builtin_amdgcn_cvt_pk_fp8_f32(x[0], x[1], 0, false);
            dw = __builtin_amdgcn_cvt_pk_fp8_f32(x[2], x[3], dw, true);
            afrag[ml][d] = dw;
        }
    }

    const float* emB = em + (size_t)b * SS * TT;
    const int tag0 = 32 * w + 4 * q;   // this lane's D rows (ml=0), inside wave block
    const int tag1 = tag0 + 16;        // (ml=1), also inside wave block

    int R0 = 0, R1 = 0, R2 = 0, R3 = 0;   // cumulative per-wave scales (exact ints)
    int cur = 0;

    // ---- init: v = exp(start + em0); per-wave pow2 renorm, post absolute R_w ----
    {
        float4 s0 = *(const float4*)(startt + tag0);
        float4 s1 = *(const float4*)(startt + tag1);
        float4 e0 = *(const float4*)(emB + tag0);
        float4 e1 = *(const float4*)(emB + tag1);
        float v0 = __expf(s0.x + e0.x), v1 = __expf(s0.y + e0.y);
        float v2 = __expf(s0.z + e0.z), v3 = __expf(s0.w + e0.w);
        float v4 = __expf(s1.x + e1.x), v5 = __expf(s1.y + e1.y);
        float v6 = __expf(s1.z + e1.z), v7 = __expf(s1.w + e1.w);
        float pm = fmaxf(fmaxf(fmaxf(v0, v1), fmaxf(v2, v3)),
                         fmaxf(fmaxf(v4, v5), fmaxf(v6, v7)));
        pm = fmaxf(pm, __shfl_xor(pm, 16));   // wave-local max (rows 32w..32w+31)
        pm = fmaxf(pm, __shfl_xor(pm, 32));
        int mg = (int)((__float_as_uint(pm) >> 23) & 0xff);
        float pk = __uint_as_float((unsigned)(255 - mg) << 23);  // 2^(128-mg)
        int d0 = __builtin_amdgcn_cvt_pk_fp8_f32(v0 * pk, v1 * pk, 0, false);
        d0 = __builtin_amdgcn_cvt_pk_fp8_f32(v2 * pk, v3 * pk, d0, true);
        int d1 = __builtin_amdgcn_cvt_pk_fp8_f32(v4 * pk, v5 * pk, 0, false);
        d1 = __builtin_amdgcn_cvt_pk_fp8_f32(v6 * pk, v7 * pk, d1, true);
        if (c == 0) {
            u8i[0][8 * w + q] = d0;
            u8i[0][8 * w + q + 4] = d1;
        }
        if (lane == 0) rS[0][w] = mg - 128;   // absolute R_w(0); step 1 adds into R=0
    }
    __syncthreads();

    // ---- one scan step (single barrier at end) ----
    auto step = [&](float4 e0, float4 e1) {
        const int4* ub = (const int4*)&u8i[cur][0];
        int4 b0 = ub[2 * q];
        int4 b1 = ub[2 * q + 1];
        int4 rr = *(const int4*)&rS[cur][0];
        R0 += rr.x; R1 += rr.y; R2 += rr.z; R3 += rr.w;
        int Rq = (q == 0) ? R0 : (q == 1) ? R1 : (q == 2) ? R2 : R3;
        int Rw = (w == 0) ? R0 : (w == 1) ? R1 : (w == 2) ? R2 : R3;
        int sb = Rq - Rw + 127;
        sb = sb < 1 ? 1 : (sb > 254 ? 254 : sb);   // E8M0, avoid NaN encoding

        // exps depend only on prefetched em -> schedule into the MFMA shadow
        float x0 = __expf(e0.x), x1 = __expf(e0.y), x2 = __expf(e0.z), x3 = __expf(e0.w);
        float x4 = __expf(e1.x), x5 = __expf(e1.y), x6 = __expf(e1.z), x7 = __expf(e1.w);

        i32x8 bb;
        bb[0] = b0.x; bb[1] = b0.y; bb[2] = b0.z; bb[3] = b0.w;
        bb[4] = b1.x; bb[5] = b1.y; bb[6] = b1.z; bb[7] = b1.w;
        f32x4 zz = {0.f, 0.f, 0.f, 0.f};
        // per-lane block scale sb repays the per-wave renorm mismatch exactly
        f32x4 a0 = __builtin_amdgcn_mfma_scale_f32_16x16x128_f8f6f4(
            afrag[0], bb, zz, 0, 0, 0, 127, 0, sb);
        f32x4 a1 = __builtin_amdgcn_mfma_scale_f32_16x16x128_f8f6f4(
            afrag[1], bb, zz, 0, 0, 0, 127, 0, sb);

        float v0 = a0[0] * x0, v1 = a0[1] * x1, v2 = a0[2] * x2, v3 = a0[3] * x3;
        float v4 = a1[0] * x4, v5 = a1[1] * x5, v6 = a1[2] * x6, v7 = a1[3] * x7;

        // EXACT per-wave renorm: current max of this wave's 32 rows -> [2,4)
        float pm = fmaxf(fmaxf(fmaxf(v0, v1), fmaxf(v2, v3)),
                         fmaxf(fmaxf(v4, v5), fmaxf(v6, v7)));
        pm = fmaxf(pm, __shfl_xor(pm, 16));
        pm = fmaxf(pm, __shfl_xor(pm, 32));
        int r = (int)((__float_as_uint(pm) >> 23) & 0xff) - 128;  // Lc - 1
        r = r < -100 ? -100 : r;
        float pk2 = __uint_as_float((unsigned)(127 - r) << 23);   // 2^-r

        int d0 = __builtin_amdgcn_cvt_pk_fp8_f32(v0 * pk2, v1 * pk2, 0, false);
        d0 = __builtin_amdgcn_cvt_pk_fp8_f32(v2 * pk2, v3 * pk2, d0, true);
        int d1 = __builtin_amdgcn_cvt_pk_fp8_f32(v4 * pk2, v5 * pk2, 0, false);
        d1 = __builtin_amdgcn_cvt_pk_fp8_f32(v6 * pk2, v7 * pk2, d1, true);
        if (c == 0) {
            int* un = &u8i[cur ^ 1][0];
            un[8 * w + q] = d0;
            un[8 * w + q + 4] = d1;
        }
        if (lane == 0) rS[cur ^ 1][w] = r;
        wg_barrier_lds();
        cur ^= 1;
    };

    // ---- main scan: groups of GRP steps, em prefetched one group ahead ----
    int k = 1;
    float4 emc0[GRP], emc1[GRP];
    #pragma unroll
    for (int g = 0; g < GRP; ++g) {
        int kk = k + g; kk = kk < SS ? kk : SS - 1;
        emc0[g] = *(const float4*)(emB + (size_t)kk * TT + tag0);
        emc1[g] = *(const float4*)(emB + (size_t)kk * TT + tag1);
    }
    while (k + GRP <= len) {
        float4 emn0[GRP], emn1[GRP];
        #pragma unroll
        for (int g = 0; g < GRP; ++g) {
            int kk = k + GRP + g; kk = kk < SS ? kk : SS - 1;
            emn0[g] = *(const float4*)(emB + (size_t)kk * TT + tag0);
            emn1[g] = *(const float4*)(emB + (size_t)kk * TT + tag1);
        }
        #pragma unroll
        for (int g = 0; g < GRP; ++g)
            step(emc0[g], emc1[g]);
        #pragma unroll
        for (int g = 0; g < GRP; ++g) { emc0[g] = emn0[g]; emc1[g] = emn1[g]; }
        k += GRP;
    }
    while (k < len) {
        float4 e0 = *(const float4*)(emB + (size_t)k * TT + tag0);
        float4 e1 = *(const float4*)(emB + (size_t)k * TT + tag1);
        step(e0, e1);
        ++k;
    }

    // ---- fold in the final posted deltas, then z ----
    __syncthreads();
    {
        int4 rr = *(const int4*)&rS[cur][0];
        R0 += rr.x; R1 += rr.y; R2 += rr.z; R3 += rr.w;
    }
    if (t < 16) {
        // thread t: rows 8t..8t+7, all in wave-block qb = t>>2
        const int* uf = &u8i[cur][0];
        int dA = uf[2 * t], dB = uf[2 * t + 1];
        const float* ep = endt + 8 * t;
        float s = 0.f;
        s += __builtin_amdgcn_cvt_f32_fp8(dA, 0) * __expf(ep[0]);
        s += __builtin_amdgcn_cvt_f32_fp8(dA, 1) * __expf(ep[1]);
        s += __builtin_amdgcn_cvt_f32_fp8(dA, 2) * __expf(ep[2]);
        s += __builtin_amdgcn_cvt_f32_fp8(dA, 3) * __expf(ep[3]);
        s += __builtin_amdgcn_cvt_f32_fp8(dB, 0) * __expf(ep[4]);
        s += __builtin_amdgcn_cvt_f32_fp8(dB, 1) * __expf(ep[5]);
        s += __builtin_amdgcn_cvt_f32_fp8(dB, 2) * __expf(ep[6]);
        s += __builtin_amdgcn_cvt_f32_fp8(dB, 3) * __expf(ep[7]);
        int qb = t >> 2;
        int Rb = (qb == 0) ? R0 : (qb == 1) ? R1 : (qb == 2) ? R2 : R3;
        int Rmx = max(max(R0, R1), max(R2, R3));
        int d = Rb - Rmx;                      // in [-few, 0]
        d = d < -126 ? -126 : d;
        float sc = __uint_as_float((unsigned)(127 + d) << 23);   // 2^d
        s *= sc;
        s += __shfl_xor(s, 1); s += __shfl_xor(s, 2);
        s += __shfl_xor(s, 4); s += __shfl_xor(s, 8);
        if (t == 0)
            zout[b] = (double)__logf(s) + (double)Rmx * 0.6931471805599453;
    }
    __syncthreads();

    // ---- posterior path score for this batch (256 threads strided) ----
    {
        const int* tg = tags + (size_t)b * SS;
        double local = 0.0; int fcnt = 0;
        for (int kk = 1 + t; kk < len; kk += 256) {
            int tp = tg[kk - 1], tc = tg[kk];
            if (mask_at(forb, mode, (size_t)tp * TT + tc)) fcnt++;
            else local += (double)trans[tp * TT + tc];
            local += (double)emB[(size_t)kk * TT + tc];
        }
        if (t == 0) {
            local += (double)startt[tg[0]] + (double)emB[tg[0]];
            local += (double)endt[tg[len - 1]];
        }
        #pragma unroll
        for (int off = 32; off >= 1; off >>= 1) {
            local += __shfl_xor(local, off);
            fcnt  += __shfl_xor(fcnt, off);
        }
        if (lane == 0) { redd[w] = local; redc[w] = fcnt; }
        __syncthreads();
        if (t == 0) {
            double tot = redd[0] + redd[1] + redd[2] + redd[3];
            int fc = redc[0] + redc[1] + redc[2] + redc[3];
            postout[b] = tot - 100000.0 * (double)fc;
        }
    }
}

// ---- nll = mean(post) - mean(z) ----
__global__ void fin_kernel(const double* __restrict__ z, const double* __restrict__ post,
                           float* __restrict__ out) {
    int t = threadIdx.x; // 64 threads, 1 wave
    double pv = post[t];
    double zv = z[t];
    #pragma unroll
    for (int off = 32; off >= 1; off >>= 1) {
        pv += __shfl_xor(pv, off);
        zv += __shfl_xor(zv, off);
    }
    if (t == 0) out[0] = (float)((pv - zv) / (double)BB);
}

extern "C" void kernel_launch(void* const* d_in, const int* in_sizes, int n_in,
                              void* d_out, int out_size, void* d_ws, size_t ws_size,
                              hipStream_t stream) {
    const float* em     = (const float*)d_in[0];
    const void*  maskp  = d_in[1];
    const int*   tags   = (const int*)d_in[2];
    const void*  forb   = d_in[3];
    const float* trans  = (const float*)d_in[4];
    const float* startt = (const float*)d_in[5];
    const float* endt   = (const float*)d_in[6];

    double* z    = (double*)d_ws;            // 64 doubles
    double* post = z + BB;                   // 64 doubles

    fwd_kernel<<<BB, 256, 0, stream>>>(em, maskp, tags, forb, trans, startt, endt, z, post);
    fin_kernel<<<1, 64, 0, stream>>>(z, post, (float*)d_out);
}